// Round 1
// baseline (184.276 us; speedup 1.0000x reference)
//
#include <hip/hip_runtime.h>
#include <math.h>

#define Bc 2
#define Vc 5
#define Cc 32
#define Dc 32
#define Hc 128
#define Wc 160
#define HWc (Hc*Wc)

// ---- workspace layout (in floats) ----
#define WS_RT    0                                   // 8 pairs * 12 floats (rot 9 + trans 3)
#define WS_KW    96                                  // 27 collapsed conv taps
#define WS_FEATT 128                                 // V*B*HW*C channel-last features
#define WS_SIM   (WS_FEATT + Vc*Bc*HWc*Cc)           // B*D*HW similarity
#define WS_PRE   (WS_SIM + Bc*Dc*HWc)                // B*D*HW prob_pre
#define WS_TOTAL (WS_PRE + Bc*Dc*HWc)

// ---- output layout (in floats) ----
#define OUT_DEPTH 0
#define OUT_CONF  (Bc*HWc)
#define OUT_PROB  (2*Bc*HWc)
#define OUT_VW    (2*Bc*HWc + Bc*Dc*HWc)

// k0: per (b, src-view v=1..4) compute rot/trans of P_v @ inv(P_0); collapse conv kernel over C.
__global__ void prep_kernel(const float* __restrict__ pm, const float* __restrict__ reg_w,
                            float* __restrict__ ws) {
    int t = threadIdx.x;
    if (t < Bc * (Vc - 1)) {
        int b = t / (Vc - 1);
        int v = t % (Vc - 1) + 1;
        float Pv[16], P0[16];
        for (int which = 0; which < 2; ++which) {
            int vv = which ? 0 : v;
            const float* E = pm + ((b * Vc + vv) * 2 + 0) * 16;
            const float* K = pm + ((b * Vc + vv) * 2 + 1) * 16;
            float* P = which ? P0 : Pv;
            for (int i = 0; i < 3; ++i)
                for (int j = 0; j < 4; ++j) {
                    float s = 0.f;
                    for (int k = 0; k < 3; ++k) s += K[i*4+k] * E[k*4+j];
                    P[i*4+j] = s;
                }
            for (int j = 0; j < 4; ++j) P[12+j] = E[12+j];
        }
        // Gauss-Jordan inverse of P0 with partial pivoting
        float A[16], I[16];
        for (int i = 0; i < 16; ++i) { A[i] = P0[i]; I[i] = (i % 5 == 0) ? 1.f : 0.f; }
        for (int col = 0; col < 4; ++col) {
            int piv = col; float best = fabsf(A[col*4+col]);
            for (int r = col+1; r < 4; ++r) { float av = fabsf(A[r*4+col]); if (av > best) { best = av; piv = r; } }
            if (piv != col)
                for (int j = 0; j < 4; ++j) {
                    float tmp = A[col*4+j]; A[col*4+j] = A[piv*4+j]; A[piv*4+j] = tmp;
                    tmp = I[col*4+j]; I[col*4+j] = I[piv*4+j]; I[piv*4+j] = tmp;
                }
            float inv = 1.f / A[col*4+col];
            for (int j = 0; j < 4; ++j) { A[col*4+j] *= inv; I[col*4+j] *= inv; }
            for (int r = 0; r < 4; ++r) if (r != col) {
                float f = A[r*4+col];
                for (int j = 0; j < 4; ++j) { A[r*4+j] -= f * A[col*4+j]; I[r*4+j] -= f * I[col*4+j]; }
            }
        }
        float M[16];
        for (int i = 0; i < 4; ++i)
            for (int j = 0; j < 4; ++j) {
                float s = 0.f;
                for (int k = 0; k < 4; ++k) s += Pv[i*4+k] * I[k*4+j];
                M[i*4+j] = s;
            }
        float* rt = ws + WS_RT + t * 12;
        for (int i = 0; i < 3; ++i)
            for (int j = 0; j < 3; ++j) rt[i*3+j] = M[i*4+j];
        rt[9] = M[3]; rt[10] = M[7]; rt[11] = M[11];
    }
    if (t >= 32 && t < 32 + 27) {
        int k = t - 32;
        float s = 0.f;
        for (int c = 0; c < Cc; ++c) s += reg_w[c * 27 + k];
        ws[WS_KW + k] = s;
    }
}

// k1: transpose (V*B, C, H*W) -> (V*B, H*W, C) via LDS tile
__global__ void transpose_kernel(const float* __restrict__ feat, float* __restrict__ ws) {
    __shared__ float tile[32][33];
    int vb = blockIdx.x;            // 0..V*B-1
    int pbase = blockIdx.y * 32;    // pixel tile base
    int tid = threadIdx.x;          // 256 threads
    int cc = tid >> 5, pp = tid & 31;
    const float* src = feat + (size_t)vb * Cc * HWc;
    #pragma unroll
    for (int i = 0; i < 4; ++i) {
        int c = cc + 8 * i;
        tile[c][pp] = src[(size_t)c * HWc + pbase + pp];
    }
    __syncthreads();
    float* dst = ws + WS_FEATT + ((size_t)vb * HWc + pbase) * Cc;
    int c2 = tid & 31, p2 = tid >> 5;
    #pragma unroll
    for (int i = 0; i < 4; ++i) {
        int p = p2 + 8 * i;
        dst[(size_t)p * Cc + c2] = tile[c2][p];
    }
}

// k2: one block per pixel (b,h,w); 128 threads = (view 0..3) x (depth 0..31)
__global__ __launch_bounds__(128) void main_kernel(
        const float* __restrict__ dvals,
        const float* __restrict__ w0, const float* __restrict__ b0,
        const float* __restrict__ w1, const float* __restrict__ b1,
        const float* __restrict__ w2, const float* __restrict__ b2,
        float* __restrict__ ws, float* __restrict__ out) {
    __shared__ float4 ref4[8];                // ref features, channel-last
    __shared__ float sS[4][Dc];
    __shared__ float vwS[4];
    __shared__ float mlpS[177];               // [0:16)w0 [16:32)b0 [32:160)w1 [160:168)b1 [168:176)w2 [176]b2

    int bid = blockIdx.x;
    int b = bid / HWc;
    int p = bid % HWc;
    int h = p / Wc;
    int w = p % Wc;
    int tid = threadIdx.x;

    if (tid < 16) mlpS[tid] = w0[tid];
    else if (tid < 32) mlpS[tid] = b0[tid - 16];
    mlpS[32 + tid] = w1[tid];                 // all 128 threads
    if (tid >= 32 && tid < 40) mlpS[128 + tid] = b1[tid - 32];   // 160..167
    if (tid >= 40 && tid < 48) mlpS[128 + tid] = w2[tid - 40];   // 168..175
    if (tid == 48) mlpS[176] = b2[0];
    if (tid < Cc) ((float*)ref4)[tid] = ws[WS_FEATT + ((size_t)b * HWc + p) * Cc + tid];
    __syncthreads();

    float4 rf[8];
    #pragma unroll
    for (int i = 0; i < 8; ++i) rf[i] = ref4[i];

    int vi = tid >> 5;     // source view index - 1
    int d  = tid & 31;

    const float* rt = ws + WS_RT + (b * 4 + vi) * 12;
    float r00 = rt[0], r01 = rt[1], r02 = rt[2];
    float r10 = rt[3], r11 = rt[4], r12 = rt[5];
    float r20 = rt[6], r21 = rt[7], r22 = rt[8];
    float t0 = rt[9], t1 = rt[10], t2 = rt[11];

    float depth = dvals[(size_t)(b * Dc + d) * HWc + p];
    float fx = (float)w, fy = (float)h;
    float px = (r00 * fx + r01 * fy + r02) * depth + t0;
    float py = (r10 * fx + r11 * fy + r12) * depth + t1;
    float pz = (r20 * fx + r21 * fy + r22) * depth + t2;
    float xs = px / pz, ys = py / pz;
    float fx0 = floorf(xs), fy0 = floorf(ys);
    float wx = xs - fx0, wy = ys - fy0;

    const float* featv = ws + WS_FEATT + (size_t)(vi + 1) * Bc * HWc * Cc + (size_t)b * HWc * Cc;

    float acc = 0.f;
    #pragma unroll
    for (int ty = 0; ty < 2; ++ty) {
        #pragma unroll
        for (int tx = 0; tx < 2; ++tx) {
            float fxt = fx0 + (float)tx;
            float fyt = fy0 + (float)ty;
            bool valid = (fxt >= 0.f) && (fxt <= (float)(Wc - 1)) &&
                         (fyt >= 0.f) && (fyt <= (float)(Hc - 1));
            float wt = (tx ? wx : 1.f - wx) * (ty ? wy : 1.f - wy);
            if (valid) {
                int ix = (int)fxt, iy = (int)fyt;
                const float4* fp = (const float4*)(featv + ((size_t)iy * Wc + ix) * Cc);
                float dot = 0.f;
                #pragma unroll
                for (int i = 0; i < 8; ++i) {
                    float4 fv = fp[i];
                    dot += fv.x * rf[i].x + fv.y * rf[i].y + fv.z * rf[i].z + fv.w * rf[i].w;
                }
                acc += wt * dot;
            }
        }
    }
    float s = acc * (1.f / (float)Cc);

    // scalar MLP: 1 -> 16 -> 8 -> 1, relu, relu, sigmoid
    float h1[16];
    #pragma unroll
    for (int i = 0; i < 16; ++i) h1[i] = fmaxf(mlpS[i] * s + mlpS[16 + i], 0.f);
    float yout = mlpS[176];
    #pragma unroll
    for (int j = 0; j < 8; ++j) {
        float a = mlpS[160 + j];
        #pragma unroll
        for (int i = 0; i < 16; ++i) a += mlpS[32 + j * 16 + i] * h1[i];
        yout += mlpS[168 + j] * fmaxf(a, 0.f);
    }
    float sig = 1.f / (1.f + __expf(-yout));

    // max over depth within each 32-lane group
    float m = sig;
    #pragma unroll
    for (int off = 16; off; off >>= 1) m = fmaxf(m, __shfl_xor(m, off));

    sS[vi][d] = s;
    if (d == 0) vwS[vi] = m;
    __syncthreads();

    if (tid < Dc) {
        float vw0 = vwS[0], vw1 = vwS[1], vw2 = vwS[2], vw3 = vwS[3];
        float wsum = 1e-5f + vw0 + vw1 + vw2 + vw3;
        float vol = sS[0][tid] * vw0 + sS[1][tid] * vw1 + sS[2][tid] * vw2 + sS[3][tid] * vw3;
        ws[WS_SIM + (size_t)(b * Dc + tid) * HWc + p] = vol / wsum;
    }
    if (tid >= 64 && tid < 68) {
        int vv = tid - 64;
        out[OUT_VW + (size_t)(b * 4 + vv) * HWc + p] = vwS[vv];
    }
}

// k3: collapsed 27-tap 3D conv with SAME zero padding, thread per (b,d,h,w)
__global__ void conv_kernel(const float* __restrict__ regb, float* __restrict__ ws) {
    int idx = blockIdx.x * 256 + threadIdx.x;
    if (idx >= Bc * Dc * HWc) return;
    int w = idx % Wc; int tmp = idx / Wc;
    int h = tmp % Hc; tmp /= Hc;
    int d = tmp % Dc; int b = tmp / Dc;
    const float* kw = ws + WS_KW;
    const float* sim = ws + WS_SIM + (size_t)b * Dc * HWc;
    float acc = 0.f;
    #pragma unroll
    for (int kd = 0; kd < 3; ++kd) {
        int dd = d + kd - 1; if (dd < 0 || dd >= Dc) continue;
        #pragma unroll
        for (int kh = 0; kh < 3; ++kh) {
            int hh = h + kh - 1; if (hh < 0 || hh >= Hc) continue;
            #pragma unroll
            for (int kwi = 0; kwi < 3; ++kwi) {
                int wwi = w + kwi - 1; if (wwi < 0 || wwi >= Wc) continue;
                acc += kw[(kd * 3 + kh) * 3 + kwi] * sim[((size_t)dd * Hc + hh) * Wc + wwi];
            }
        }
    }
    ws[WS_PRE + idx] = acc + regb[0];
}

// k4: per-pixel softmax over D, argmax -> depth, max prob -> conf
__global__ void softmax_kernel(const float* __restrict__ dvals,
                               const float* __restrict__ ws, float* __restrict__ out) {
    int idx = blockIdx.x * 256 + threadIdx.x;
    if (idx >= Bc * HWc) return;
    int b = idx / HWc; int p = idx % HWc;
    const float* preb = ws + WS_PRE + (size_t)b * Dc * HWc + p;
    float pre[Dc];
    float m = -1e30f; int am = 0;
    #pragma unroll
    for (int d = 0; d < Dc; ++d) {
        float v = preb[(size_t)d * HWc];
        pre[d] = v;
        if (v > m) { m = v; am = d; }
    }
    float sum = 0.f;
    #pragma unroll
    for (int d = 0; d < Dc; ++d) { pre[d] = __expf(pre[d] - m); sum += pre[d]; }
    float inv = 1.f / sum;
    #pragma unroll
    for (int d = 0; d < Dc; ++d)
        out[OUT_PROB + (size_t)b * Dc * HWc + (size_t)d * HWc + p] = pre[d] * inv;
    out[OUT_DEPTH + idx] = dvals[(size_t)(b * Dc + am) * HWc + p];
    out[OUT_CONF + idx] = inv;
}

extern "C" void kernel_launch(void* const* d_in, const int* in_sizes, int n_in,
                              void* d_out, int out_size, void* d_ws, size_t ws_size,
                              hipStream_t stream) {
    const float* features = (const float*)d_in[0];   // (V,B,C,H,W)
    const float* pm       = (const float*)d_in[1];   // (B,V,2,4,4)
    const float* dvals    = (const float*)d_in[2];   // (B,D,H,W)
    const float* pw_w0    = (const float*)d_in[3];
    const float* pw_b0    = (const float*)d_in[4];
    const float* pw_w1    = (const float*)d_in[5];
    const float* pw_b1    = (const float*)d_in[6];
    const float* pw_w2    = (const float*)d_in[7];
    const float* pw_b2    = (const float*)d_in[8];
    const float* reg_w    = (const float*)d_in[9];   // (1,C,3,3,3)
    const float* reg_b    = (const float*)d_in[10];
    float* out = (float*)d_out;
    float* ws  = (float*)d_ws;

    prep_kernel<<<1, 64, 0, stream>>>(pm, reg_w, ws);
    transpose_kernel<<<dim3(Vc * Bc, HWc / 32), 256, 0, stream>>>(features, ws);
    main_kernel<<<Bc * HWc, 128, 0, stream>>>(dvals, pw_w0, pw_b0, pw_w1, pw_b1,
                                              pw_w2, pw_b2, ws, out);
    conv_kernel<<<(Bc * Dc * HWc + 255) / 256, 256, 0, stream>>>(reg_b, ws);
    softmax_kernel<<<(Bc * HWc + 255) / 256, 256, 0, stream>>>(dvals, ws, out);
}

// Round 2
// 167.344 us; speedup vs baseline: 1.1012x; 1.1012x over previous
//
#include <hip/hip_runtime.h>
#include <math.h>

#define Bc 2
#define Vc 5
#define Cc 32
#define Dc 32
#define Hc 128
#define Wc 160
#define HWc (Hc*Wc)

// ---- workspace layout (in floats) ----
#define WS_RT    0                                   // 8 pairs * 12 floats (rot 9 + trans 3)
#define WS_KW    96                                  // 27 collapsed conv taps
#define WS_FEATT 128                                 // (V*B, HW, C) channel-last features
#define WS_DVT   (WS_FEATT + Vc*Bc*HWc*Cc)           // (B, HW, D) depth values, d-last
#define WS_SIMT  (WS_DVT + Bc*HWc*Dc)                // (B, HW, D) similarity, d-last
#define WS_PRET  (WS_SIMT + Bc*HWc*Dc)               // (B, HW, D) prob_pre, d-last

// ---- output layout (in floats) ----
#define OUT_DEPTH 0
#define OUT_CONF  (Bc*HWc)
#define OUT_PROB  (2*Bc*HWc)
#define OUT_VW    (2*Bc*HWc + Bc*Dc*HWc)

// k0: per (b, src-view v=1..4) compute rot/trans of P_v @ inv(P_0); collapse conv kernel over C.
__global__ void prep_kernel(const float* __restrict__ pm, const float* __restrict__ reg_w,
                            float* __restrict__ ws) {
    int t = threadIdx.x;
    if (t < Bc * (Vc - 1)) {
        int b = t / (Vc - 1);
        int v = t % (Vc - 1) + 1;
        float Pv[16], P0[16];
        for (int which = 0; which < 2; ++which) {
            int vv = which ? 0 : v;
            const float* E = pm + ((b * Vc + vv) * 2 + 0) * 16;
            const float* K = pm + ((b * Vc + vv) * 2 + 1) * 16;
            float* P = which ? P0 : Pv;
            for (int i = 0; i < 3; ++i)
                for (int j = 0; j < 4; ++j) {
                    float s = 0.f;
                    for (int k = 0; k < 3; ++k) s += K[i*4+k] * E[k*4+j];
                    P[i*4+j] = s;
                }
            for (int j = 0; j < 4; ++j) P[12+j] = E[12+j];
        }
        float A[16], I[16];
        for (int i = 0; i < 16; ++i) { A[i] = P0[i]; I[i] = (i % 5 == 0) ? 1.f : 0.f; }
        for (int col = 0; col < 4; ++col) {
            int piv = col; float best = fabsf(A[col*4+col]);
            for (int r = col+1; r < 4; ++r) { float av = fabsf(A[r*4+col]); if (av > best) { best = av; piv = r; } }
            if (piv != col)
                for (int j = 0; j < 4; ++j) {
                    float tmp = A[col*4+j]; A[col*4+j] = A[piv*4+j]; A[piv*4+j] = tmp;
                    tmp = I[col*4+j]; I[col*4+j] = I[piv*4+j]; I[piv*4+j] = tmp;
                }
            float inv = 1.f / A[col*4+col];
            for (int j = 0; j < 4; ++j) { A[col*4+j] *= inv; I[col*4+j] *= inv; }
            for (int r = 0; r < 4; ++r) if (r != col) {
                float f = A[r*4+col];
                for (int j = 0; j < 4; ++j) { A[r*4+j] -= f * A[col*4+j]; I[r*4+j] -= f * I[col*4+j]; }
            }
        }
        float M[16];
        for (int i = 0; i < 4; ++i)
            for (int j = 0; j < 4; ++j) {
                float s = 0.f;
                for (int k = 0; k < 4; ++k) s += Pv[i*4+k] * I[k*4+j];
                M[i*4+j] = s;
            }
        float* rt = ws + WS_RT + t * 12;
        for (int i = 0; i < 3; ++i)
            for (int j = 0; j < 3; ++j) rt[i*3+j] = M[i*4+j];
        rt[9] = M[3]; rt[10] = M[7]; rt[11] = M[11];
    }
    if (t >= 32 && t < 32 + 27) {
        int k = t - 32;
        float s = 0.f;
        for (int c = 0; c < Cc; ++c) s += reg_w[c * 27 + k];
        ws[WS_KW + k] = s;
    }
}

// k1: transpose 32xHW slabs to HWx32. slabs 0..9 = features (V*B), 10..11 = dvals (B)
__global__ void transpose_kernel(const float* __restrict__ feat, const float* __restrict__ dvals,
                                 float* __restrict__ ws) {
    __shared__ float tile[32][33];
    int slab = blockIdx.x;          // 0..11
    int pbase = blockIdx.y * 32;    // pixel tile base
    int tid = threadIdx.x;          // 256 threads
    const float* src; float* dst;
    if (slab < Vc * Bc) {
        src = feat + (size_t)slab * Cc * HWc;
        dst = ws + WS_FEATT + (size_t)slab * HWc * Cc;
    } else {
        int b = slab - Vc * Bc;
        src = dvals + (size_t)b * Dc * HWc;
        dst = ws + WS_DVT + (size_t)b * HWc * Dc;
    }
    int cc = tid >> 5, pp = tid & 31;
    #pragma unroll
    for (int i = 0; i < 4; ++i) {
        int c = cc + 8 * i;
        tile[c][pp] = src[(size_t)c * HWc + pbase + pp];
    }
    __syncthreads();
    int c2 = tid & 31, p2 = tid >> 5;
    #pragma unroll
    for (int i = 0; i < 4; ++i) {
        int p = p2 + 8 * i;
        dst[((size_t)(pbase + p)) * 32 + c2] = tile[c2][p];
    }
}

// k2: block = 8 pixels x 32 depths; thread = (pixel, depth), loops over the 4 source views
__global__ __launch_bounds__(256) void main_kernel(
        const float* __restrict__ w0, const float* __restrict__ b0,
        const float* __restrict__ w1, const float* __restrict__ b1,
        const float* __restrict__ w2, const float* __restrict__ b2,
        float* __restrict__ ws, float* __restrict__ out) {
    __shared__ float mlpS[177];   // [0:16)w0 [16:32)b0 [32:160)w1 [160:168)b1 [168:176)w2 [176]b2
    __shared__ float rtS[48];     // 4 views x 12

    int bid = blockIdx.x;                 // B*HW/8 blocks
    int b = bid / (HWc / 8);
    int pblk = (bid % (HWc / 8)) * 8;
    int tid = threadIdx.x;
    int d = tid & 31;
    int pg = tid >> 5;
    int p = pblk + pg;
    int h = p / Wc, w = p % Wc;

    if (tid < 16) mlpS[tid] = w0[tid];
    else if (tid < 32) mlpS[tid] = b0[tid - 16];
    else if (tid < 160) mlpS[tid] = w1[tid - 32];
    else if (tid < 168) mlpS[tid] = b1[tid - 160];
    else if (tid < 176) mlpS[tid] = w2[tid - 168];
    else if (tid == 176) mlpS[176] = b2[0];
    if (tid >= 192 && tid < 240) rtS[tid - 192] = ws[WS_RT + b * 48 + (tid - 192)];
    __syncthreads();

    // ref features (broadcast within each 32-lane depth group)
    const float4* refp = (const float4*)(ws + WS_FEATT + ((size_t)b * HWc + p) * Cc);
    float4 rf[8];
    #pragma unroll
    for (int i = 0; i < 8; ++i) rf[i] = refp[i];

    float depth = ws[WS_DVT + ((size_t)b * HWc + p) * Dc + d];
    float fx = (float)w, fy = (float)h;

    float sv[4];
    #pragma unroll
    for (int v = 0; v < 4; ++v) {
        const float* rt = rtS + v * 12;
        float px = (rt[0] * fx + rt[1] * fy + rt[2]) * depth + rt[9];
        float py = (rt[3] * fx + rt[4] * fy + rt[5]) * depth + rt[10];
        float pz = (rt[6] * fx + rt[7] * fy + rt[8]) * depth + rt[11];
        float xs = __fdividef(px, pz);
        float ys = __fdividef(py, pz);
        float fx0 = floorf(xs), fy0 = floorf(ys);
        float wx = xs - fx0, wy = ys - fy0;

        const float* featv = ws + WS_FEATT + ((size_t)((v + 1) * Bc + b)) * HWc * Cc;
        float acc = 0.f;
        #pragma unroll
        for (int ty = 0; ty < 2; ++ty) {
            #pragma unroll
            for (int tx = 0; tx < 2; ++tx) {
                float fxt = fx0 + (float)tx;
                float fyt = fy0 + (float)ty;
                bool valid = (fxt >= 0.f) && (fxt <= (float)(Wc - 1)) &&
                             (fyt >= 0.f) && (fyt <= (float)(Hc - 1));
                float wt = (tx ? wx : 1.f - wx) * (ty ? wy : 1.f - wy);
                if (valid) {
                    int ix = (int)fxt, iy = (int)fyt;
                    const float4* fp = (const float4*)(featv + ((size_t)iy * Wc + ix) * Cc);
                    float dot = 0.f;
                    #pragma unroll
                    for (int i = 0; i < 8; ++i) {
                        float4 fv = fp[i];
                        dot += fv.x * rf[i].x + fv.y * rf[i].y + fv.z * rf[i].z + fv.w * rf[i].w;
                    }
                    acc += wt * dot;
                }
            }
        }
        sv[v] = acc * (1.f / (float)Cc);
    }

    // 4-wide scalar MLP: 1 -> 16 -> 8 -> 1 (relu, relu, sigmoid), one lane eval per view
    float h1[16][4];
    #pragma unroll
    for (int i = 0; i < 16; ++i) {
        float a = mlpS[i], bb = mlpS[16 + i];
        #pragma unroll
        for (int v = 0; v < 4; ++v) h1[i][v] = fmaxf(a * sv[v] + bb, 0.f);
    }
    float bias2 = mlpS[176];
    float y[4] = {bias2, bias2, bias2, bias2};
    const float4* w1v = (const float4*)(mlpS + 32);
    #pragma unroll
    for (int j = 0; j < 8; ++j) {
        float a0 = mlpS[160 + j];
        float acc[4] = {a0, a0, a0, a0};
        #pragma unroll
        for (int k = 0; k < 4; ++k) {
            float4 wq = w1v[j * 4 + k];
            #pragma unroll
            for (int v = 0; v < 4; ++v) {
                acc[v] += wq.x * h1[4*k+0][v] + wq.y * h1[4*k+1][v]
                        + wq.z * h1[4*k+2][v] + wq.w * h1[4*k+3][v];
            }
        }
        float w2j = mlpS[168 + j];
        #pragma unroll
        for (int v = 0; v < 4; ++v) y[v] += w2j * fmaxf(acc[v], 0.f);
    }

    float vw[4];
    #pragma unroll
    for (int v = 0; v < 4; ++v) {
        float m = __fdividef(1.f, 1.f + __expf(-y[v]));
        #pragma unroll
        for (int off = 16; off; off >>= 1) m = fmaxf(m, __shfl_xor(m, off));
        vw[v] = m;    // max over the 32 depths of this pixel, same on all lanes
    }

    float wsum = 1e-5f + vw[0] + vw[1] + vw[2] + vw[3];
    float vol = sv[0] * vw[0] + sv[1] * vw[1] + sv[2] * vw[2] + sv[3] * vw[3];
    ws[WS_SIMT + ((size_t)b * HWc + p) * Dc + d] = __fdividef(vol, wsum);

    if (d < 4) {
        float x = (d == 0) ? vw[0] : (d == 1) ? vw[1] : (d == 2) ? vw[2] : vw[3];
        out[OUT_VW + ((size_t)b * 4 + d) * HWc + p] = x;
    }
}

// k3: collapsed 27-tap 3D conv, pixel-major layout; thread = (b, p, q) computing 4 depth outputs
__global__ __launch_bounds__(256) void conv_kernel(const float* __restrict__ regb,
                                                   float* __restrict__ ws) {
    int idx = blockIdx.x * 256 + threadIdx.x;   // B*HW*8
    int q = idx & 7;
    int pp = idx >> 3;
    int p = pp % HWc, b = pp / HWc;
    int h = p / Wc, w = p % Wc;

    float kw[27];
    #pragma unroll
    for (int i = 0; i < 27; ++i) kw[i] = ws[WS_KW + i];

    const float* simb = ws + WS_SIMT + (size_t)b * HWc * Dc;
    float pre0 = 0.f, pre1 = 0.f, pre2 = 0.f, pre3 = 0.f;
    #pragma unroll
    for (int kh = 0; kh < 3; ++kh) {
        int hh = h + kh - 1; if (hh < 0 || hh >= Hc) continue;
        #pragma unroll
        for (int kwi = 0; kwi < 3; ++kwi) {
            int wwp = w + kwi - 1; if (wwp < 0 || wwp >= Wc) continue;
            const float4* col = (const float4*)(simb + ((size_t)hh * Wc + wwp) * Dc);
            float c0 = 0.f, c5 = 0.f;
            if (q > 0) c0 = col[q - 1].w;
            float4 mid = col[q];
            if (q < 7) c5 = col[q + 1].x;
            float k0 = kw[0*9 + kh*3 + kwi];
            float k1 = kw[1*9 + kh*3 + kwi];
            float k2 = kw[2*9 + kh*3 + kwi];
            pre0 += k0 * c0    + k1 * mid.x + k2 * mid.y;
            pre1 += k0 * mid.x + k1 * mid.y + k2 * mid.z;
            pre2 += k0 * mid.y + k1 * mid.z + k2 * mid.w;
            pre3 += k0 * mid.z + k1 * mid.w + k2 * c5;
        }
    }
    float bb = regb[0];
    float4 r; r.x = pre0 + bb; r.y = pre1 + bb; r.z = pre2 + bb; r.w = pre3 + bb;
    *(float4*)(ws + WS_PRET + ((size_t)b * HWc + p) * Dc + q * 4) = r;
}

// k4: softmax over D; 4 threads per pixel (lane layout [t:2][pw:4]), shfl-combined
__global__ __launch_bounds__(256) void softmax_kernel(const float* __restrict__ ws,
                                                      float* __restrict__ out) {
    int idx = blockIdx.x * 256 + threadIdx.x;   // B*HW*4
    int lane = idx & 63;
    int t = lane >> 4;
    int pw = lane & 15;
    int P = (idx >> 6) * 16 + pw;               // 0..B*HW-1
    int b = P / HWc, p = P % HWc;

    const float4* pre4 = (const float4*)(ws + WS_PRET + ((size_t)b * HWc + p) * Dc + t * 8);
    float4 a = pre4[0], bq = pre4[1];
    float pr[8] = {a.x, a.y, a.z, a.w, bq.x, bq.y, bq.z, bq.w};

    float m = pr[0]; int am = t * 8;
    #pragma unroll
    for (int k = 1; k < 8; ++k) if (pr[k] > m) { m = pr[k]; am = t * 8 + k; }
    #pragma unroll
    for (int s = 16; s <= 32; s <<= 1) {
        float om = __shfl_xor(m, s);
        int oi = __shfl_xor(am, s);
        if (om > m || (om == m && oi < am)) { m = om; am = oi; }
    }
    float e[8]; float sum = 0.f;
    #pragma unroll
    for (int k = 0; k < 8; ++k) { e[k] = __expf(pr[k] - m); sum += e[k]; }
    #pragma unroll
    for (int s = 16; s <= 32; s <<= 1) sum += __shfl_xor(sum, s);
    float inv = __fdividef(1.f, sum);
    #pragma unroll
    for (int k = 0; k < 8; ++k)
        out[OUT_PROB + ((size_t)b * Dc + t * 8 + k) * HWc + p] = e[k] * inv;
    if (t == 0) {
        out[OUT_DEPTH + (size_t)b * HWc + p] = ws[WS_DVT + ((size_t)b * HWc + p) * Dc + am];
        out[OUT_CONF + (size_t)b * HWc + p] = inv;   // exp(max - max) / sum
    }
}

extern "C" void kernel_launch(void* const* d_in, const int* in_sizes, int n_in,
                              void* d_out, int out_size, void* d_ws, size_t ws_size,
                              hipStream_t stream) {
    const float* features = (const float*)d_in[0];   // (V,B,C,H,W)
    const float* pm       = (const float*)d_in[1];   // (B,V,2,4,4)
    const float* dvals    = (const float*)d_in[2];   // (B,D,H,W)
    const float* pw_w0    = (const float*)d_in[3];
    const float* pw_b0    = (const float*)d_in[4];
    const float* pw_w1    = (const float*)d_in[5];
    const float* pw_b1    = (const float*)d_in[6];
    const float* pw_w2    = (const float*)d_in[7];
    const float* pw_b2    = (const float*)d_in[8];
    const float* reg_w    = (const float*)d_in[9];   // (1,C,3,3,3)
    const float* reg_b    = (const float*)d_in[10];
    float* out = (float*)d_out;
    float* ws  = (float*)d_ws;

    prep_kernel<<<1, 64, 0, stream>>>(pm, reg_w, ws);
    transpose_kernel<<<dim3(Vc * Bc + Bc, HWc / 32), 256, 0, stream>>>(features, dvals, ws);
    main_kernel<<<Bc * HWc / 8, 256, 0, stream>>>(pw_w0, pw_b0, pw_w1, pw_b1,
                                                  pw_w2, pw_b2, ws, out);
    conv_kernel<<<(Bc * HWc * 8) / 256, 256, 0, stream>>>(reg_b, ws);
    softmax_kernel<<<(Bc * HWc * 4) / 256, 256, 0, stream>>>(ws, out);
}